// Round 2
// baseline (6995.056 us; speedup 1.0000x reference)
//
#include <hip/hip_runtime.h>
#include <math.h>

#define B_N   32
#define T_N   1024
#define INDIM 60
#define DM_   256
#define L_N   4
#define DS_   32
#define DC_   4
#define DI_   512
#define DTR_  16
#define NTOK  (B_N * T_N)   // 32768

__device__ __forceinline__ float softplus_f(float x) {
    return x > 20.f ? x : log1pf(__expf(x));
}
__device__ __forceinline__ float silu_f(float x) {
    return x / (1.f + __expf(-x));
}

// ---------------------------------------------------------------------------
// Generic f32 GEMM:  C[M,N] = act(A[M,K] (row stride lda) * W[N,K]^T + bias)
// optionally accumulating into C. 64x64 tile, BK=16, 256 threads, 4x4/thread.
// M is always a multiple of 64 here; N and K handled generically.
// ---------------------------------------------------------------------------
template<int HAS_BIAS, int ACCUM>
__global__ __launch_bounds__(256) void gemm_bt_kernel(
    const float* __restrict__ A, int lda,
    const float* __restrict__ W,
    const float* __restrict__ bias,
    float* __restrict__ C, int ldc,
    int N, int K)
{
    __shared__ float As[16][68];   // [k][m], stride 68 keeps 16B alignment
    __shared__ float Ws[16][68];   // [k][n]
    const int tid = threadIdx.x;
    const int tx = tid & 15, ty = tid >> 4;
    const int m0 = blockIdx.x * 64;
    const int n0 = blockIdx.y * 64;
    const int li = tid >> 2;          // 0..63 row within tile
    const int lj = (tid & 3) << 2;    // 0,4,8,12 k-offset

    float acc[4][4] = {};

    for (int k0 = 0; k0 < K; k0 += 16) {
        const int gk = k0 + lj;
        // ---- stage A tile (64 rows x 16 k) ----
        {
            const float* src = A + (size_t)(m0 + li) * lda + gk;
            float4 v;
            if (gk + 3 < K) {
                v = *(const float4*)src;
            } else {
                v.x = (gk + 0 < K) ? src[0] : 0.f;
                v.y = (gk + 1 < K) ? src[1] : 0.f;
                v.z = (gk + 2 < K) ? src[2] : 0.f;
                v.w = (gk + 3 < K) ? src[3] : 0.f;
            }
            As[lj + 0][li] = v.x; As[lj + 1][li] = v.y;
            As[lj + 2][li] = v.z; As[lj + 3][li] = v.w;
        }
        // ---- stage W tile (64 n-rows x 16 k) ----
        {
            const int gn = n0 + li;
            float4 v = make_float4(0.f, 0.f, 0.f, 0.f);
            if (gn < N) {
                const float* src = W + (size_t)gn * K + gk;
                if (gk + 3 < K) {
                    v = *(const float4*)src;
                } else {
                    v.x = (gk + 0 < K) ? src[0] : 0.f;
                    v.y = (gk + 1 < K) ? src[1] : 0.f;
                    v.z = (gk + 2 < K) ? src[2] : 0.f;
                    v.w = (gk + 3 < K) ? src[3] : 0.f;
                }
            }
            Ws[lj + 0][li] = v.x; Ws[lj + 1][li] = v.y;
            Ws[lj + 2][li] = v.z; Ws[lj + 3][li] = v.w;
        }
        __syncthreads();
        #pragma unroll
        for (int k = 0; k < 16; ++k) {
            float a0 = As[k][ty * 4 + 0], a1 = As[k][ty * 4 + 1];
            float a2 = As[k][ty * 4 + 2], a3 = As[k][ty * 4 + 3];
            float b0 = Ws[k][tx * 4 + 0], b1 = Ws[k][tx * 4 + 1];
            float b2 = Ws[k][tx * 4 + 2], b3 = Ws[k][tx * 4 + 3];
            acc[0][0] += a0 * b0; acc[0][1] += a0 * b1; acc[0][2] += a0 * b2; acc[0][3] += a0 * b3;
            acc[1][0] += a1 * b0; acc[1][1] += a1 * b1; acc[1][2] += a1 * b2; acc[1][3] += a1 * b3;
            acc[2][0] += a2 * b0; acc[2][1] += a2 * b1; acc[2][2] += a2 * b2; acc[2][3] += a2 * b3;
            acc[3][0] += a3 * b0; acc[3][1] += a3 * b1; acc[3][2] += a3 * b2; acc[3][3] += a3 * b3;
        }
        __syncthreads();
    }

    const int mb = m0 + ty * 4;
    const int nb = n0 + tx * 4;
    #pragma unroll
    for (int r = 0; r < 4; ++r) {
        float* dst = C + (size_t)(mb + r) * ldc + nb;
        if (nb + 3 < N) {
            float4 v = make_float4(acc[r][0], acc[r][1], acc[r][2], acc[r][3]);
            if (HAS_BIAS) {
                float4 bs = *(const float4*)(bias + nb);
                v.x += bs.x; v.y += bs.y; v.z += bs.z; v.w += bs.w;
            }
            if (ACCUM) {
                float4 o = *(const float4*)dst;
                v.x += o.x; v.y += o.y; v.z += o.z; v.w += o.w;
            }
            *(float4*)dst = v;
        } else {
            #pragma unroll
            for (int c = 0; c < 4; ++c) {
                if (nb + c >= N) continue;
                float x = acc[r][c];
                if (HAS_BIAS) x += bias[nb + c];
                if (ACCUM) x += dst[c];
                dst[c] = x;
            }
        }
    }
}

// ---------------------------------------------------------------------------
// LayerNorm(+bias,gamma) + ReLU over DM=256; one token per block.
// ---------------------------------------------------------------------------
__global__ __launch_bounds__(256) void ln_relu_kernel(
    const float* __restrict__ in, const float* __restrict__ g,
    const float* __restrict__ b, float* __restrict__ out)
{
    const int row = blockIdx.x;
    const int d = threadIdx.x;
    const float v = in[(size_t)row * DM_ + d];
    float s = v, s2 = v * v;
    #pragma unroll
    for (int off = 1; off < 64; off <<= 1) {
        s  += __shfl_xor(s, off);
        s2 += __shfl_xor(s2, off);
    }
    __shared__ float sm[8];
    const int wid = threadIdx.x >> 6, lane = threadIdx.x & 63;
    if (lane == 0) { sm[wid] = s; sm[4 + wid] = s2; }
    __syncthreads();
    s  = sm[0] + sm[1] + sm[2] + sm[3];
    s2 = sm[4] + sm[5] + sm[6] + sm[7];
    const float mean = s * (1.f / DM_);
    const float var  = s2 * (1.f / DM_) - mean * mean;
    const float o = (v - mean) * rsqrtf(var + 1e-5f) * g[d] + b[d];
    out[(size_t)row * DM_ + d] = fmaxf(o, 0.f);
}

// ---------------------------------------------------------------------------
// RMSNorm over DM=256; one token per block.
// ---------------------------------------------------------------------------
__global__ __launch_bounds__(256) void rmsnorm_kernel(
    const float* __restrict__ in, const float* __restrict__ g,
    float* __restrict__ out)
{
    const int row = blockIdx.x;
    const int d = threadIdx.x;
    const float v = in[(size_t)row * DM_ + d];
    float s2 = v * v;
    #pragma unroll
    for (int off = 1; off < 64; off <<= 1) s2 += __shfl_xor(s2, off);
    __shared__ float sm[4];
    const int wid = threadIdx.x >> 6, lane = threadIdx.x & 63;
    if (lane == 0) sm[wid] = s2;
    __syncthreads();
    s2 = sm[0] + sm[1] + sm[2] + sm[3];
    out[(size_t)row * DM_ + d] = v * rsqrtf(s2 * (1.f / DM_) + 1e-6f) * g[d];
}

// ---------------------------------------------------------------------------
// Causal depthwise conv (DC=4) over x_in (chunk-local, stride DI) + SiLU.
// idx over ntok_c * DI.
// ---------------------------------------------------------------------------
__global__ __launch_bounds__(256) void conv_silu_kernel(
    const float* __restrict__ xin, const float* __restrict__ cw,
    const float* __restrict__ cb, float* __restrict__ xc)
{
    const int idx = blockIdx.x * 256 + threadIdx.x;
    const int d  = idx & (DI_ - 1);
    const int bt = idx >> 9;
    const int t  = bt & (T_N - 1);   // chunks start at batch boundaries
    const float4 w = *(const float4*)(cw + d * 4);   // taps k=0..3
    const size_t base = (size_t)bt * DI_ + d;
    float acc = cb[d] + w.w * xin[base];             // k=3 -> t
    if (t >= 1) acc += w.z * xin[base - 1 * DI_];    // k=2 -> t-1
    if (t >= 2) acc += w.y * xin[base - 2 * DI_];    // k=1 -> t-2
    if (t >= 3) acc += w.x * xin[base - 3 * DI_];    // k=0 -> t-3
    xc[idx] = acc * (1.f / (1.f + __expf(-acc)));
}

// ---------------------------------------------------------------------------
// Fused selective scan:
//   delta = softplus(x_dbl[:, :16] @ dtw^T + dtb)   (computed in-register)
//   momentum recurrence over T
//   y = (scan_y + d_skip*xc) * silu(z)              (combine fused)
// Block = 64 d-values x 4 s-groups (8 s each). Grid = nb_chunk * 8.
// ---------------------------------------------------------------------------
__global__ __launch_bounds__(256) void scan_fused_kernel(
    const float* __restrict__ xdbl,    // (nb,T,80): dt|B|C (chunk-local)
    const float* __restrict__ xc,      // (nb,T,DI)
    const float* __restrict__ z,       // (nb,T,DI)
    const float* __restrict__ dtw,     // (DI,16)
    const float* __restrict__ dtb,     // (DI)
    const float* __restrict__ alog,    // (DI,DS)
    const float* __restrict__ dskip,   // (DI)
    const float* __restrict__ alpha_p,
    const float* __restrict__ beta_p,
    float* __restrict__ y)             // (nb,T,DI)
{
    const int b  = blockIdx.x >> 3;
    const int d0 = (blockIdx.x & 7) << 6;
    const int dl = threadIdx.x >> 2;
    const int sg = threadIdx.x & 3;
    const int d  = d0 + dl;
    const float alpha = alpha_p[0];
    const float beta  = beta_p[0];
    const float na = 1.f - alpha;
    const float dsk = dskip[d];
    const float dtbv = dtb[d];

    float wdt[16];
    #pragma unroll
    for (int r = 0; r < 4; ++r) {
        const float4 w4 = *(const float4*)(dtw + d * 16 + r * 4);
        wdt[r*4+0] = w4.x; wdt[r*4+1] = w4.y; wdt[r*4+2] = w4.z; wdt[r*4+3] = w4.w;
    }
    float A[8];
    #pragma unroll
    for (int j = 0; j < 8; ++j) A[j] = -__expf(alog[d * DS_ + sg * 8 + j]);

    float hs[8] = {0,0,0,0,0,0,0,0};
    float vs[8] = {0,0,0,0,0,0,0,0};

    size_t bt = (size_t)b * T_N;
    for (int t = 0; t < T_N; ++t, ++bt) {
        const float* row = xdbl + bt * 80;
        // delta = softplus(dot(dt_row, wdt) + dtb)
        float dtdot = dtbv;
        #pragma unroll
        for (int r = 0; r < 4; ++r) {
            const float4 q = *(const float4*)(row + r * 4);
            dtdot += q.x * wdt[r*4+0] + q.y * wdt[r*4+1]
                   + q.z * wdt[r*4+2] + q.w * wdt[r*4+3];
        }
        const float dlt = softplus_f(dtdot);
        const float xt  = xc[bt * DI_ + d];
        const float4 B0 = *(const float4*)(row + 16 + sg * 8);
        const float4 B1 = *(const float4*)(row + 20 + sg * 8);
        const float4 C0 = *(const float4*)(row + 48 + sg * 8);
        const float4 C1 = *(const float4*)(row + 52 + sg * 8);
        const float Bv[8] = {B0.x,B0.y,B0.z,B0.w,B1.x,B1.y,B1.z,B1.w};
        const float Cv[8] = {C0.x,C0.y,C0.z,C0.w,C1.x,C1.y,C1.z,C1.w};
        const float dx = dlt * xt;
        float ysum = 0.f;
        #pragma unroll
        for (int j = 0; j < 8; ++j) {
            const float dA  = __expf(dlt * A[j]);
            const float dBx = dx * Bv[j];
            vs[j] = beta * vs[j] + dBx;
            hs[j] = dA * hs[j] + (alpha * vs[j] + na * dBx);
            ysum += hs[j] * Cv[j];
        }
        ysum += __shfl_xor(ysum, 1);
        ysum += __shfl_xor(ysum, 2);
        if (sg == 0) {
            const float zv = z[bt * DI_ + d];
            y[bt * DI_ + d] = (ysum + dsk * xt) * silu_f(zv);
        }
    }
}

// ---------------------------------------------------------------------------
extern "C" void kernel_launch(void* const* d_in, const int* in_sizes, int n_in,
                              void* d_out, int out_size, void* d_ws, size_t ws_size,
                              hipStream_t stream)
{
    const float* x     = (const float*)d_in[0];
    const float* fe_w  = (const float*)d_in[1];
    const float* fe_b  = (const float*)d_in[2];
    const float* ln_g  = (const float*)d_in[3];
    const float* ln_b  = (const float*)d_in[4];
    const float* bng   = (const float*)d_in[5];
    const float* inw   = (const float*)d_in[6];
    const float* convw = (const float*)d_in[7];
    const float* convb = (const float*)d_in[8];
    const float* xpw   = (const float*)d_in[9];
    const float* dtw   = (const float*)d_in[10];
    const float* dtb   = (const float*)d_in[11];
    const float* alog  = (const float*)d_in[12];
    const float* dskip = (const float*)d_in[13];
    const float* outw  = (const float*)d_in[14];
    const float* alpha = (const float*)d_in[15];
    const float* beta  = (const float*)d_in[16];
    const float* rmsg  = (const float*)d_in[17];

    // -------- workspace layout, adaptive to ws_size --------
    // h (B,T,DM) persistent + per-chunk: u (Mc,DM) | x_in/y (Mc,DI) |
    // z (Mc,DI) | xc (Mc,DI); x_dbl (Mc,80) overlays u.
    const size_t avail = ws_size / 4;  // floats
    int nb = 32;
    while (nb > 4 && 8388608ULL + (size_t)nb * 1024 * 1792 > avail) nb >>= 1;
    const int ntok_c = nb * 1024;

    float* ws   = (float*)d_ws;
    float* h    = ws;                                   // 8,388,608 f32
    float* u    = ws + 8388608;                         // ntok_c*256 (also x_dbl)
    float* xiny = u    + (size_t)ntok_c * 256;          // ntok_c*512 (x_in, then y)
    float* z    = xiny + (size_t)ntok_c * 512;          // ntok_c*512
    float* xc   = z    + (size_t)ntok_c * 512;          // ntok_c*512

    float* pre = (float*)d_out;  // pre-LN temp; fully rewritten at the end

    const dim3 blk(256);

    // feature extract: pre = x @ fe_w^T + fe_b
    gemm_bt_kernel<1,0><<<dim3(NTOK/64, DM_/64), blk, 0, stream>>>(
        x, INDIM, fe_w, fe_b, pre, DM_, DM_, INDIM);
    // h = relu(LN(pre))
    ln_relu_kernel<<<dim3(NTOK), blk, 0, stream>>>(pre, ln_g, ln_b, h);

    for (int l = 0; l < L_N; ++l) {
        const float* inw_l  = inw  + (size_t)l * 2 * DI_ * DM_;
        const float* xpw_l  = xpw  + (size_t)l * 80 * DI_;
        const float* dtw_l  = dtw  + (size_t)l * DI_ * DTR_;
        const float* outw_l = outw + (size_t)l * DM_ * DI_;

        for (int b0 = 0; b0 < B_N; b0 += nb) {
            float* h_c = h + (size_t)b0 * 1024 * DM_;
            // u = rmsnorm(h_c) * blk_norm_g[l]
            rmsnorm_kernel<<<dim3(ntok_c), blk, 0, stream>>>(h_c, bng + l * DM_, u);
            // x_in = u @ inw[0:DI]^T ; z = u @ inw[DI:2DI]^T
            gemm_bt_kernel<0,0><<<dim3(ntok_c/64, DI_/64), blk, 0, stream>>>(
                u, DM_, inw_l, nullptr, xiny, DI_, DI_, DM_);
            gemm_bt_kernel<0,0><<<dim3(ntok_c/64, DI_/64), blk, 0, stream>>>(
                u, DM_, inw_l + (size_t)DI_ * DM_, nullptr, z, DI_, DI_, DM_);
            // xc = silu(causal_conv(x_in) + cb)
            conv_silu_kernel<<<dim3((ntok_c * DI_) / 256), blk, 0, stream>>>(
                xiny, convw + l * DI_ * DC_, convb + l * DI_, xc);
            // x_dbl (overlays u) = xc @ x_proj_w[l]^T   (ntok_c,80)
            gemm_bt_kernel<0,0><<<dim3(ntok_c/64, 2), blk, 0, stream>>>(
                xc, DI_, xpw_l, nullptr, u, 80, 80, DI_);
            // fused scan -> y (overlays x_in)
            scan_fused_kernel<<<dim3(nb * 8), blk, 0, stream>>>(
                u, xc, z, dtw_l, dtb + l * DI_, alog + (size_t)l * DI_ * DS_,
                dskip + l * DI_, alpha + l, beta + l, xiny);
            // h_c += y @ out_proj_w[l]^T
            gemm_bt_kernel<0,1><<<dim3(ntok_c/64, DM_/64), blk, 0, stream>>>(
                xiny, DI_, outw_l, nullptr, h_c, DM_, DM_, DI_);
        }
    }

    // out = rmsnorm(h) * rms_g
    rmsnorm_kernel<<<dim3(NTOK), blk, 0, stream>>>(h, rmsg, (float*)d_out);
}